// Round 2
// baseline (1419.881 us; speedup 1.0000x reference)
//
#include <hip/hip_runtime.h>

typedef short v8s __attribute__((ext_vector_type(8)));
typedef float v4f __attribute__((ext_vector_type(4)));

#define T_TOK 2048
#define DD 2048
#define FF 4096
#define EE 8
#define BMG 256        // row-tile granularity (both GEMMs)
#define MT1 24         // max m-tiles: (4096 + 8*255) rounded up to 256 => 6144/256
#define MAXROWS 6144

// workspace layout (bytes)
#define WS_COUNTS 0
#define WS_FILL   32
#define WS_ROWOFF 64
#define WS_TOPE   128
#define WS_TOPW   (WS_TOPE + T_TOK * 2 * 4)    // 16512
#define WS_IDS    (WS_TOPW + T_TOK * 2 * 4)    // 32896
#define WS_WTS    (WS_IDS + MAXROWS * 4)       // 57472
#define WS_ZERO   (WS_WTS + MAXROWS * 4)       // 82048 bytes zeroed each launch
#define WS_H      82176ul                      // 256-aligned; bf16 H[6144][4096]

// Swizzle: conflict-free (floor) for BOTH stride-1 frag reads and stride-4
// staging writes. fl = row within [64][64-bf16] subtile, kb = byte col (x16).
#define SWZ8(r) (((((r) ^ ((r) >> 3)) & 7)) << 4)
#define TADDR(fl, kb) ((fl) * 128 + ((kb) ^ SWZ8(fl)))

#define LGKM0() asm volatile("s_waitcnt lgkmcnt(0)" ::: "memory")
#define BARR()  __builtin_amdgcn_s_barrier()
#define CFENCE() asm volatile("" ::: "memory")

static __device__ __forceinline__ short f2bf(float f) {
  return __builtin_bit_cast(short, static_cast<__bf16>(f));
}

// ---------------- router: fp32 logits, softmax, top-2 ----------------
__global__ __launch_bounds__(256) void router_k(
    const float* __restrict__ x, const float* __restrict__ gw,
    int* __restrict__ counts, int* __restrict__ tope, float* __restrict__ topw) {
  const int lane = threadIdx.x & 63;
  const int t = blockIdx.x * 4 + (threadIdx.x >> 6);
  if (t >= T_TOK) return;
  float acc[EE] = {0.f, 0.f, 0.f, 0.f, 0.f, 0.f, 0.f, 0.f};
  const float* xr = x + (size_t)t * DD;
  for (int i = 0; i < DD / 64; ++i) {
    int k = i * 64 + lane;
    float xv = xr[k];
    const v4f* g = (const v4f*)(gw + (size_t)k * EE);
    v4f g0 = g[0], g1 = g[1];
    acc[0] += xv * g0[0]; acc[1] += xv * g0[1]; acc[2] += xv * g0[2]; acc[3] += xv * g0[3];
    acc[4] += xv * g1[0]; acc[5] += xv * g1[1]; acc[6] += xv * g1[2]; acc[7] += xv * g1[3];
  }
  #pragma unroll
  for (int e = 0; e < EE; ++e) {
    #pragma unroll
    for (int off = 32; off > 0; off >>= 1) acc[e] += __shfl_xor(acc[e], off);
  }
  if (lane == 0) {
    float m = acc[0];
    #pragma unroll
    for (int e = 1; e < EE; ++e) m = fmaxf(m, acc[e]);
    float p[EE], s = 0.f;
    #pragma unroll
    for (int e = 0; e < EE; ++e) { p[e] = expf(acc[e] - m); s += p[e]; }
    float inv = 1.f / s;
    #pragma unroll
    for (int e = 0; e < EE; ++e) p[e] *= inv;
    int e1 = 0;
    #pragma unroll
    for (int e = 1; e < EE; ++e) if (p[e] > p[e1]) e1 = e;
    int e2 = (e1 == 0) ? 1 : 0;
    #pragma unroll
    for (int e = 0; e < EE; ++e) if (e != e1 && p[e] > p[e2]) e2 = e;
    tope[2 * t] = e1;  tope[2 * t + 1] = e2;
    topw[2 * t] = p[e1]; topw[2 * t + 1] = p[e2];
    atomicAdd(&counts[e1], 1);
    atomicAdd(&counts[e2], 1);
  }
}

// ---------------- per-expert padded row offsets (granularity 256) ----------------
__global__ void offsets_k(const int* __restrict__ counts, int* __restrict__ rowoff) {
  if (threadIdx.x == 0) {
    int off = 0;
    #pragma unroll
    for (int e = 0; e < EE; ++e) {
      rowoff[e] = off;
      off += ((counts[e] + BMG - 1) / BMG) * BMG;
    }
  }
}

// ---------------- scatter token ids/weights into expert-sorted slots ----------------
__global__ __launch_bounds__(256) void scatter_k(
    const int* __restrict__ tope, const float* __restrict__ topw,
    const int* __restrict__ rowoff, int* __restrict__ fill,
    int* __restrict__ ids, float* __restrict__ wts) {
  const int t = blockIdx.x * 256 + threadIdx.x;
  if (t >= T_TOK) return;
  #pragma unroll
  for (int j = 0; j < 2; ++j) {
    int e = tope[2 * t + j];
    int pos = rowoff[e] + atomicAdd(&fill[e], 1);
    ids[pos] = t;
    wts[pos] = topw[2 * t + j];
  }
}

// ======================= GEMM1: H = silu(X@W1) * (X@W3) =======================
// block: 256 rows x 128 f-cols, computing BOTH mats (eff 256x256). 8 waves.
// wave (wr = wid>>2, wc = wid&3): mat = wc>>1, col64 = (wc&1)*64; tile 128x64.
// A (gathered token rows, fp32) -> direct global->reg with cvt.
// B (w1,w3) -> fp32 reg-staged -> bf16 LDS, double-buffered, raw barriers.
__global__ __launch_bounds__(512, 2) void gemm1_k(
    const float* __restrict__ x, const float* __restrict__ w1,
    const float* __restrict__ w3, const int* __restrict__ counts,
    const int* __restrict__ rowoff, const int* __restrict__ ids,
    unsigned short* __restrict__ H) {
  const int nt = blockIdx.x, mt = blockIdx.y;
  int expert = -1;
  #pragma unroll
  for (int e = 0; e < EE; ++e) {
    int rs = rowoff[e];
    int tl = (counts[e] + BMG - 1) >> 8;
    if (mt * BMG >= rs && mt * BMG < rs + tl * BMG) expert = e;
  }
  if (expert < 0) return;
  const int m0 = mt * BMG, n0 = nt * 128;

  __shared__ char smem[65536];   // 2 bufs x 32KB; reused (64KB) by epilogue

  const int tid = threadIdx.x;
  const int lane = tid & 63;
  const int wid = tid >> 6;
  const int lr = lane & 15, lg = lane >> 4;
  const int wr = wid >> 2;           // 0..1 : row half
  const int wc = wid & 3;            // 0..3 : subtile = mat*2 + colhalf
  const int mat = wc >> 1;
  const int c64 = (wc & 1) * 64;
  const int bsub = wc * 8192;        // this wave's B subtile byte base

  // A row pointers (gathered tokens); pad slots have ids=0 -> valid row 0.
  const float* ap[8];
  #pragma unroll
  for (int m = 0; m < 8; ++m)
    ap[m] = x + (size_t)ids[m0 + wr * 128 + m * 16 + lr] * DD + lg * 8;

  // B staging: 512 thr cover 2 mats x 128 f x 64 k fp32. smat=tid>>8.
  const int smat = tid >> 8;
  const int sr = tid & 255;
  const int f4 = (sr & 31) * 4;
  const int k8 = (sr >> 5) * 8;
  const float* wsrc = (smat ? w3 : w1) + (size_t)expert * DD * FF
                      + (size_t)k8 * FF + n0 + f4;

  v4f srg[8];
  #define G1_ISSUE(KT) { const float* sp = wsrc + (size_t)(KT) * 64 * FF;       \
    _Pragma("unroll") for (int j = 0; j < 8; ++j)                               \
      srg[j] = *(const v4f*)(sp + (size_t)j * FF); }
  #define G1_WRITE(BUF) { _Pragma("unroll") for (int c = 0; c < 4; ++c) {       \
      v8s h; _Pragma("unroll") for (int j = 0; j < 8; ++j) h[j] = f2bf(srg[j][c]); \
      int fg = f4 + c;                                                          \
      *(v8s*)(smem + (BUF) * 32768 + (smat * 2 + (fg >> 6)) * 8192              \
              + TADDR((fg & 63), k8 * 2)) = h; } }

  v4f acc[8][4];
  #pragma unroll
  for (int i = 0; i < 8; ++i)
    #pragma unroll
    for (int j = 0; j < 4; ++j) acc[i][j] = (v4f){0.f, 0.f, 0.f, 0.f};

  G1_ISSUE(0);
  G1_WRITE(0);
  G1_ISSUE(1);
  LGKM0(); BARR(); CFENCE();

  const int NKT = DD / 64;  // 32
  #pragma unroll 2
  for (int kt = 0; kt < NKT; ++kt) {
    const int cur = kt & 1;
    // ---- compute phase on buf cur ----
    #pragma unroll
    for (int ks = 0; ks < 2; ++ks) {
      v8s b0 = *(const v8s*)(smem + cur * 32768 + bsub + TADDR(0 * 16 + lr, ks * 64 + lg * 16));
      v8s b1 = *(const v8s*)(smem + cur * 32768 + bsub + TADDR(1 * 16 + lr, ks * 64 + lg * 16));
      v8s b2 = *(const v8s*)(smem + cur * 32768 + bsub + TADDR(2 * 16 + lr, ks * 64 + lg * 16));
      v8s b3 = *(const v8s*)(smem + cur * 32768 + bsub + TADDR(3 * 16 + lr, ks * 64 + lg * 16));
      #pragma unroll
      for (int m = 0; m < 8; ++m) {
        const float* p = ap[m] + kt * 64 + ks * 32;
        v4f u0 = *(const v4f*)p;
        v4f u1 = *(const v4f*)(p + 4);
        v8s av;
        av[0] = f2bf(u0[0]); av[1] = f2bf(u0[1]); av[2] = f2bf(u0[2]); av[3] = f2bf(u0[3]);
        av[4] = f2bf(u1[0]); av[5] = f2bf(u1[1]); av[6] = f2bf(u1[2]); av[7] = f2bf(u1[3]);
        acc[m][0] = __builtin_amdgcn_mfma_f32_16x16x32_bf16(av, b0, acc[m][0], 0, 0, 0);
        acc[m][1] = __builtin_amdgcn_mfma_f32_16x16x32_bf16(av, b1, acc[m][1], 0, 0, 0);
        acc[m][2] = __builtin_amdgcn_mfma_f32_16x16x32_bf16(av, b2, acc[m][2], 0, 0, 0);
        acc[m][3] = __builtin_amdgcn_mfma_f32_16x16x32_bf16(av, b3, acc[m][3], 0, 0, 0);
      }
    }
    LGKM0(); CFENCE(); BARR(); CFENCE();
    // ---- staging phase: write buf for kt+1, issue loads for kt+2 ----
    if (kt + 1 < NKT) {
      G1_WRITE(1 - cur);
      if (kt + 2 < NKT) G1_ISSUE(kt + 2);
      LGKM0();
    }
    CFENCE(); BARR(); CFENCE();
  }

  // ---- epilogue: exchange w3 acc via LDS, silu-combine, store H (bf16) ----
  const int ebase = (wr * 2 + (wc & 1)) * 16384;
  #pragma unroll
  for (int pass = 0; pass < 2; ++pass) {
    if (mat == 1) {
      #pragma unroll
      for (int mm = 0; mm < 4; ++mm) {
        #pragma unroll
        for (int n = 0; n < 4; ++n) {
          int col = n * 16 + lr;
          *(v4f*)(smem + ebase + col * 256 + ((mm * 64 + lg * 16) ^ SWZ8(col))) =
              acc[pass * 4 + mm][n];
        }
      }
    }
    LGKM0(); CFENCE(); BARR(); CFENCE();
    if (mat == 0) {
      #pragma unroll
      for (int mm = 0; mm < 4; ++mm) {
        int m = pass * 4 + mm;
        #pragma unroll
        for (int n = 0; n < 4; ++n) {
          int col = n * 16 + lr;
          v4f up = *(const v4f*)(smem + ebase + col * 256 + ((mm * 64 + lg * 16) ^ SWZ8(col)));
          #pragma unroll
          for (int r = 0; r < 4; ++r) {
            float g = acc[m][n][r];
            float hv = (g / (1.f + expf(-g))) * up[r];
            H[(size_t)(m0 + wr * 128 + m * 16 + lg * 4 + r) * FF
              + (n0 + c64 + n * 16 + lr)] = (unsigned short)f2bf(hv);
          }
        }
      }
    }
    CFENCE(); BARR(); CFENCE();
  }
}

// ======================= GEMM2: out[tok] += w * (H @ W2) =======================
// block: 256 rows x 256 d-cols. 8 waves, wave tile 128x64. A = H (bf16) direct
// global->reg (no cvt, with pre-barrier ks0 prefetch). B = W2 staged to LDS.
__global__ __launch_bounds__(512, 2) void gemm2_k(
    const unsigned short* __restrict__ H, const float* __restrict__ w2,
    const int* __restrict__ counts, const int* __restrict__ rowoff,
    const int* __restrict__ ids, const float* __restrict__ wts,
    float* __restrict__ out) {
  const int nt = blockIdx.x, mt = blockIdx.y;
  int expert = -1;
  #pragma unroll
  for (int e = 0; e < EE; ++e) {
    int rs = rowoff[e];
    int tl = (counts[e] + BMG - 1) >> 8;
    if (mt * BMG >= rs && mt * BMG < rs + tl * BMG) expert = e;
  }
  if (expert < 0) return;
  const int m0 = mt * BMG, n0 = nt * 256;

  __shared__ char smem[65536];

  const int tid = threadIdx.x;
  const int lane = tid & 63;
  const int wid = tid >> 6;
  const int lr = lane & 15, lg = lane >> 4;
  const int wr = wid >> 2;          // 0..1
  const int wq = wid & 3;           // 0..3 : 64-col quarter
  const int bsub = wq * 8192;

  const unsigned short* hp[8];
  #pragma unroll
  for (int m = 0; m < 8; ++m)
    hp[m] = H + (size_t)(m0 + wr * 128 + m * 16 + lr) * FF + lg * 8;

  // B staging: 512 thr cover 256 d x 64 k fp32.
  const int d4 = (tid & 63) * 4;
  const int k8 = (tid >> 6) * 8;
  const float* wsrc = w2 + (size_t)expert * FF * DD + (size_t)k8 * DD + n0 + d4;

  v4f srg[8];
  #define G2_ISSUE(KT) { const float* sp = wsrc + (size_t)(KT) * 64 * DD;       \
    _Pragma("unroll") for (int j = 0; j < 8; ++j)                               \
      srg[j] = *(const v4f*)(sp + (size_t)j * DD); }
  #define G2_WRITE(BUF) { _Pragma("unroll") for (int c = 0; c < 4; ++c) {       \
      v8s h; _Pragma("unroll") for (int j = 0; j < 8; ++j) h[j] = f2bf(srg[j][c]); \
      int dg = d4 + c;                                                          \
      *(v8s*)(smem + (BUF) * 32768 + (dg >> 6) * 8192                           \
              + TADDR((dg & 63), k8 * 2)) = h; } }

  v4f acc[8][4];
  #pragma unroll
  for (int i = 0; i < 8; ++i)
    #pragma unroll
    for (int j = 0; j < 4; ++j) acc[i][j] = (v4f){0.f, 0.f, 0.f, 0.f};

  v8s apre[8];
  #define G2_APRE(KT) { _Pragma("unroll") for (int m = 0; m < 8; ++m)           \
      apre[m] = *(const v8s*)(hp[m] + (KT) * 64); }

  G2_ISSUE(0);
  G2_WRITE(0);
  G2_ISSUE(1);
  G2_APRE(0);                 // ks0 A-frags of kt=0 in flight across barrier
  LGKM0(); BARR(); CFENCE();

  const int NKT = FF / 64;  // 64
  #pragma unroll 2
  for (int kt = 0; kt < NKT; ++kt) {
    const int cur = kt & 1;
    // ---- compute phase ----
    #pragma unroll
    for (int ks = 0; ks < 2; ++ks) {
      v8s b0 = *(const v8s*)(smem + cur * 32768 + bsub + TADDR(0 * 16 + lr, ks * 64 + lg * 16));
      v8s b1 = *(const v8s*)(smem + cur * 32768 + bsub + TADDR(1 * 16 + lr, ks * 64 + lg * 16));
      v8s b2 = *(const v8s*)(smem + cur * 32768 + bsub + TADDR(2 * 16 + lr, ks * 64 + lg * 16));
      v8s b3 = *(const v8s*)(smem + cur * 32768 + bsub + TADDR(3 * 16 + lr, ks * 64 + lg * 16));
      #pragma unroll
      for (int m = 0; m < 8; ++m) {
        v8s av = ks ? *(const v8s*)(hp[m] + kt * 64 + 32) : apre[m];
        acc[m][0] = __builtin_amdgcn_mfma_f32_16x16x32_bf16(av, b0, acc[m][0], 0, 0, 0);
        acc[m][1] = __builtin_amdgcn_mfma_f32_16x16x32_bf16(av, b1, acc[m][1], 0, 0, 0);
        acc[m][2] = __builtin_amdgcn_mfma_f32_16x16x32_bf16(av, b2, acc[m][2], 0, 0, 0);
        acc[m][3] = __builtin_amdgcn_mfma_f32_16x16x32_bf16(av, b3, acc[m][3], 0, 0, 0);
      }
    }
    LGKM0(); CFENCE(); BARR(); CFENCE();
    // ---- staging phase ----
    if (kt + 1 < NKT) {
      G2_WRITE(1 - cur);
      if (kt + 2 < NKT) G2_ISSUE(kt + 2);
      G2_APRE(kt + 1);        // issue next ks0 A-frags pre-barrier
      LGKM0();
    }
    CFENCE(); BARR(); CFENCE();
  }

  // ---- epilogue: weighted atomic scatter-add (skip zero-weight pad rows) ----
  #pragma unroll
  for (int m = 0; m < 8; ++m) {
    #pragma unroll
    for (int r = 0; r < 4; ++r) {
      int row = m0 + wr * 128 + m * 16 + lg * 4 + r;
      float wgt = wts[row];
      if (wgt != 0.f) {
        float* orow = out + (size_t)ids[row] * DD + n0 + wq * 64 + lr;
        #pragma unroll
        for (int n = 0; n < 4; ++n)
          atomicAdd(orow + n * 16, wgt * acc[m][n][r]);
      }
    }
  }
}

extern "C" void kernel_launch(void* const* d_in, const int* in_sizes, int n_in,
                              void* d_out, int out_size, void* d_ws, size_t ws_size,
                              hipStream_t stream) {
  const float* x  = (const float*)d_in[0];
  const float* gw = (const float*)d_in[1];
  const float* w1 = (const float*)d_in[2];
  const float* w3 = (const float*)d_in[3];
  const float* w2 = (const float*)d_in[4];
  float* out = (float*)d_out;
  char* ws = (char*)d_ws;

  int*   counts = (int*)(ws + WS_COUNTS);
  int*   fill   = (int*)(ws + WS_FILL);
  int*   rowoff = (int*)(ws + WS_ROWOFF);
  int*   tope   = (int*)(ws + WS_TOPE);
  float* topw   = (float*)(ws + WS_TOPW);
  int*   ids    = (int*)(ws + WS_IDS);
  float* wts    = (float*)(ws + WS_WTS);
  unsigned short* H = (unsigned short*)(ws + WS_H);

  hipMemsetAsync(ws, 0, WS_ZERO, stream);
  hipMemsetAsync(d_out, 0, (size_t)out_size * sizeof(float), stream);

  router_k<<<T_TOK / 4, 256, 0, stream>>>(x, gw, counts, tope, topw);
  offsets_k<<<1, 64, 0, stream>>>(counts, rowoff);
  scatter_k<<<T_TOK / 256, 256, 0, stream>>>(tope, topw, rowoff, fill, ids, wts);
  gemm1_k<<<dim3(FF / 128, MT1), 512, 0, stream>>>(x, w1, w3, counts, rowoff, ids, H);
  gemm2_k<<<dim3(DD / 256, MT1), 512, 0, stream>>>(H, w2, counts, rowoff, ids, wts, out);
}